// Round 4
// baseline (777.645 us; speedup 1.0000x reference)
//
#include <hip/hip_runtime.h>
#include <hip/hip_bf16.h>

#define TSTEPS 64
#define NTOT   8192
#define FDIM   256
#define HDIM   256
#define ROWS   32
#define NTHR   1024

typedef __attribute__((ext_vector_type(8))) short bf16x8;
typedef __attribute__((ext_vector_type(4))) float f32x4;

__device__ __forceinline__ short f2bf(float f) {
    union { float f; unsigned u; } v; v.f = f;
    unsigned r = v.u + 0x7FFFu + ((v.u >> 16) & 1u);
    return (short)(r >> 16);
}

// lgkm-only barrier: does NOT drain vmcnt, so global prefetch loads stay in
// flight across it. Single asm block so nothing can be scheduled between the
// waitcnt and the barrier.
__device__ __forceinline__ void bar_lgkm() {
    asm volatile("s_waitcnt lgkmcnt(0)\n\ts_barrier" ::: "memory");
}

// One block (1024 thr, 16 waves) owns ROWS=32 rows of N for all T steps.
// Wave w computes output cols [16w, 16w+16). Weights live in registers as
// MFMA B-fragments: 32 regs per matrix per lane (64 total) + acc 8 + xld 8
// + temps ~= 115 regs. __launch_bounds__(1024,1): 1 block/CU = 4 waves/SIMD
// -> 128-VGPR cap -> NO SPILL (R2/R3 failed here: 190 regs vs 128 cap).
// LDS: double-buffered swizzled bf16 x/h tiles + LN scratch, 2 barriers/step.
__global__ __launch_bounds__(NTHR, 1)
void rnn_ln_fused(const float* __restrict__ X,
                  const float* __restrict__ W_ih,
                  const float* __restrict__ W_hh,
                  const float* __restrict__ b_ih,
                  const float* __restrict__ b_hh,
                  const float* __restrict__ ln_w,
                  const float* __restrict__ ln_b,
                  float* __restrict__ out)
{
    __shared__ char smem[4*16384 + 4096 + 256];
    char* xb0 = smem;                 // x tile buf 0 [32][256] bf16, swizzled
    char* xb1 = smem + 16384;         // x tile buf 1
    char* hb0 = smem + 32768;         // h tile buf 0
    char* hb1 = smem + 49152;         // h tile buf 1
    float* psum = (float*)(smem + 65536);          // [32 rows][16 waves][2]
    float* mrs  = (float*)(smem + 65536 + 4096);   // [32 rows][2] (mean, rstd)

    const int tid  = threadIdx.x;
    const int lane = tid & 63;
    const int wv   = tid >> 6;     // wave 0..15
    const int l15  = lane & 15;
    const int l4   = lane >> 4;    // 0..3
    const int n0   = blockIdx.x * ROWS;

    // ---- weight fragments into registers (once) ----
    // B-frag mfma_16x16x32: lane holds col=l15, k=l4*8+e within kk*32 chunk
    bf16x8 wih[8], whh[8];
    #pragma unroll
    for (int kk = 0; kk < 8; ++kk) {
        const int wr = wv*16 + l15;       // weight row = output col
        const int wk = kk*32 + l4*8;
        const float* p = W_ih + wr*FDIM + wk;
        const float* q = W_hh + wr*HDIM + wk;
        bf16x8 fi, fh;
        #pragma unroll
        for (int e = 0; e < 8; ++e) { fi[e] = f2bf(p[e]); fh[e] = f2bf(q[e]); }
        wih[kk] = fi; whh[kk] = fh;
    }

    const int ccol = wv*16 + l15;     // this lane's output column
    const float bc = b_ih[ccol] + b_hh[ccol];
    const float lw = ln_w[ccol];
    const float lb = ln_b[ccol];

    f32x4 acc[2];      // C: col=l15, row=l4*4+j (+16*tr)
    f32x4 xld[2];      // staged X tile (f32), two steps ahead of LDS

    auto load_x = [&](int t) {
        const f32x4* base = (const f32x4*)(X + ((size_t)t * NTOT + n0) * FDIM);
        #pragma unroll
        for (int k = 0; k < 2; ++k) xld[k] = base[k*1024 + tid];  // coalesced 16KB/k
    };
    auto store_x = [&](char* xbuf) {  // row = 16k+wv, col-byte = lane*8; swizzled
        #pragma unroll
        for (int k = 0; k < 2; ++k) {
            const int row = 16*k + wv;
            int off = row*512 + lane*8;
            off ^= (row & 7) << 4;
            unsigned lo = (unsigned)(unsigned short)f2bf(xld[k].x) |
                          ((unsigned)(unsigned short)f2bf(xld[k].y) << 16);
            unsigned hi = (unsigned)(unsigned short)f2bf(xld[k].z) |
                          ((unsigned)(unsigned short)f2bf(xld[k].w) << 16);
            uint2 v; v.x = lo; v.y = hi;
            *(uint2*)(xbuf + off) = v;
        }
    };
    auto mm = [&](const char* buf, const bf16x8 (&wf)[8]) {
        #pragma unroll
        for (int kk = 0; kk < 8; ++kk) {
            const int co = kk*64 + l4*16;
            const int r0 = l15, r1 = l15 + 16;
            const int sw = (l15 & 7) << 4;          // r0&7 == r1&7
            bf16x8 a0 = *(const bf16x8*)(buf + ((r0*512 + co) ^ sw));
            bf16x8 a1 = *(const bf16x8*)(buf + ((r1*512 + co) ^ sw));
            acc[0] = __builtin_amdgcn_mfma_f32_16x16x32_bf16(a0, wf[kk], acc[0], 0, 0, 0);
            acc[1] = __builtin_amdgcn_mfma_f32_16x16x32_bf16(a1, wf[kk], acc[1], 0, 0, 0);
        }
    };
    auto zero_acc = [&]() {
        acc[0] = f32x4{0.f, 0.f, 0.f, 0.f};
        acc[1] = f32x4{0.f, 0.f, 0.f, 0.f};
    };
    auto write_h = [&](char* hbuf, bool addbias) {
        #pragma unroll
        for (int tr = 0; tr < 2; ++tr)
            #pragma unroll
            for (int j = 0; j < 4; ++j) {
                const int row = tr*16 + l4*4 + j;
                const int rs = row*512, sw = (row & 7) << 4;
                float v = acc[tr][j];
                if (addbias) v += bc;
                *(short*)(hbuf + ((rs + ccol*2) ^ sw)) = f2bf(v);
            }
    };

    // ================= prologue =================
    load_x(0);
    store_x(xb0);                 // x_0 -> xb0
    load_x(1);
    bar_lgkm();

    zero_acc();
    mm(xb0, wih);                 // acc = xw_0
    store_x(xb1);                 // x_1 -> xb1
    load_x(2);                    // xld = x_2
    write_h(hb0, true);           // h0 = xw_0 + b_ih + b_hh (no relu)
    bar_lgkm();

    // ================= main loop =================
    // entry invariants: hb[t&1]=c_t, acc=xw_t, xb[(t+1)&1]=x_{t+1} (t<63),
    //                   xld=x_{t+2} (t<62)
    #pragma unroll 1
    for (int t = 0; t < TSTEPS; ++t) {
        char* hcur = (t & 1) ? hb1 : hb0;
        char* hnxt = (t & 1) ? hb0 : hb1;
        char* xrd  = (t & 1) ? xb0 : xb1;   // x_{t+1}
        char* xwr  = (t & 1) ? xb1 : xb0;   // dest for x_{t+2}

        mm(hcur, whh);                       // acc = xw_t + c_t W_hh^T

        // c_{t+1} = relu(acc + bc)
        #pragma unroll
        for (int tr = 0; tr < 2; ++tr) {
            f32x4 v = acc[tr];
            #pragma unroll
            for (int j = 0; j < 4; ++j) v[j] = fmaxf(v[j] + bc, 0.f);
            acc[tr] = v;
        }

        // LN partials: reduce this wave's 16 cols -> psum[row][wv]
        #pragma unroll
        for (int tr = 0; tr < 2; ++tr) {
            float s[4], q[4];
            #pragma unroll
            for (int j = 0; j < 4; ++j) { s[j] = acc[tr][j]; q[j] = s[j]*s[j]; }
            #pragma unroll
            for (int m = 1; m < 16; m <<= 1) {
                #pragma unroll
                for (int j = 0; j < 4; ++j) {
                    s[j] += __shfl_xor(s[j], m);
                    q[j] += __shfl_xor(q[j], m);
                }
            }
            if (l15 == 0) {
                #pragma unroll
                for (int j = 0; j < 4; ++j) {
                    const int row = tr*16 + l4*4 + j;
                    float2 w; w.x = s[j]; w.y = q[j];
                    *(float2*)(psum + (row*16 + wv)*2) = w;
                }
            }
        }

        if (t < 63) write_h(hnxt, false);    // c_{t+1} -> other h buffer

        bar_lgkm();                          // (A) psum + hnxt visible

        // parallel LN finalize: 16 lanes per row, waves 0-7
        if (tid < 512) {
            const int row = tid >> 4, p = tid & 15;
            const float2 v = *(const float2*)(psum + (row*16 + p)*2);
            float S = v.x, Q = v.y;
            S += __shfl_xor(S, 1); Q += __shfl_xor(Q, 1);
            S += __shfl_xor(S, 2); Q += __shfl_xor(Q, 2);
            S += __shfl_xor(S, 4); Q += __shfl_xor(Q, 4);
            S += __shfl_xor(S, 8); Q += __shfl_xor(Q, 8);
            if (p == 0) {
                const float mean = S * (1.f/256.f);
                const float var  = Q * (1.f/256.f) - mean * mean;
                float2 w; w.x = mean; w.y = rsqrtf(var + 1e-5f);
                *(float2*)(mrs + row*2) = w;
            }
        }
        if (t < 62) store_x(xwr);            // x_{t+2} -> xwr

        bar_lgkm();                          // (B) mrs visible; xwr staged

        if (t < 61) load_x(t + 3);           // issue next prefetch ASAP

        // normalize + store out[t]
        float* op = out + ((size_t)t * NTOT + n0) * HDIM;
        #pragma unroll
        for (int tr = 0; tr < 2; ++tr)
            #pragma unroll
            for (int j = 0; j < 4; ++j) {
                const int row = tr*16 + l4*4 + j;
                const float2 ms = *(const float2*)(mrs + row*2);
                op[row*HDIM + ccol] = (acc[tr][j] - ms.x) * ms.y * lw + lb;
            }

        if (t < 63) {
            zero_acc();
            mm(xrd, wih);                    // acc = xw_{t+1}
        }
    }
}

extern "C" void kernel_launch(void* const* d_in, const int* in_sizes, int n_in,
                              void* d_out, int out_size, void* d_ws, size_t ws_size,
                              hipStream_t stream) {
    const float* X   = (const float*)d_in[0];
    const float* Wih = (const float*)d_in[1];
    const float* Whh = (const float*)d_in[2];
    const float* bih = (const float*)d_in[3];
    const float* bhh = (const float*)d_in[4];
    const float* lnw = (const float*)d_in[5];
    const float* lnb = (const float*)d_in[6];
    float* out = (float*)d_out;

    rnn_ln_fused<<<dim3(NTOT / ROWS), dim3(NTHR), 0, stream>>>(
        X, Wih, Whh, bih, bhh, lnw, lnb, out);
}